// Round 11
// baseline (530.213 us; speedup 1.0000x reference)
//
#include <hip/hip_runtime.h>

// ---- problem constants ----
#define BB 8
#define NN 20000
#define KK 9
#define KC 576                 // KK*64
#define ROWS (BB*NN)           // 160000
#define CHUNKS 313             // ceil(NN/64)

// ---- workspace layout (ushort elements) ----
#define WST_ELE   36864                 // conv_w chunks [18][64][32]
#define WST2_ELE  4096                  // mlp_w chunks  [2][64][32]
#define ADJ_ELE   (NN*88)               // adj rows padded 81->88 bf16
#define XB_ELE    (ROWS*64)             // x in bf16, row NN-1 per batch zeroed
#define WST_OFF   0
#define WST2_OFF  36864
#define ADJ_OFF   40960                 // byte 81,920 (16B aligned)
#define XB_OFF    (ADJ_OFF + ADJ_ELE)   // elem 1,800,960
#define CTR_OFF   (XB_OFF + XB_ELE)     // elem 12,040,960 -> byte 24,081,920 (64B aligned)
// total ws use: ~24.1 MB + 64 B

typedef __bf16 bf16x8 __attribute__((ext_vector_type(8)));
typedef float  f32x4  __attribute__((ext_vector_type(4)));
typedef unsigned short u16x8 __attribute__((ext_vector_type(8)));
typedef unsigned u32x4 __attribute__((ext_vector_type(4)));

__device__ __forceinline__ unsigned short f2bf(float f) {
    unsigned u = __builtin_bit_cast(unsigned, f);
    u += 0x7FFFu + ((u >> 16) & 1u);          // RNE
    return (unsigned short)(u >> 16);
}
__device__ __forceinline__ float bfhi2f(unsigned w) { return __builtin_bit_cast(float, w & 0xFFFF0000u); }
__device__ __forceinline__ float bflo2f(unsigned w) { return __builtin_bit_cast(float, w << 16); }
__device__ __forceinline__ float elu_f(float v) { return v > 0.0f ? v : (__expf(v) - 1.0f); }

// ---------------------------------------------------------------------------
// Prep: x -> bf16 (row NN-1 per batch zeroed), adj -> bf16 padded rows,
// conv_w / mlp_w -> MFMA chunk order, zero the 8 XCD claim counters.
// ---------------------------------------------------------------------------
__global__ void __launch_bounds__(256) paiconv_prep(
        const float* __restrict__ x,       // [ROWS][64]
        const float* __restrict__ adj,     // [NN][81]
        const float* __restrict__ conv_w,  // [64][576]
        const float* __restrict__ mlp_w,   // [64][64]
        unsigned short* __restrict__ ws16) {
    const int tid = blockIdx.x * 256 + threadIdx.x;

    if (tid < 16) {                            // claim counters (re-zeroed every launch)
        ((int*)(ws16 + CTR_OFF))[tid] = 0;
    }
    if (tid < XB_ELE / 8) {                    // 1,280,000 threads: 8 elems each
        const int e = tid * 8;
        const int r = e >> 6;                  // global row
        const int n = r % NN;                  // within-batch row
        u16x8 pk;
        if (n == NN - 1) {
            #pragma unroll
            for (int i = 0; i < 8; ++i) pk[i] = 0;   // pre-masked row
        } else {
            f32x4 lo = *(const f32x4*)(x + e);
            f32x4 hi = *(const f32x4*)(x + e + 4);
            #pragma unroll
            for (int i = 0; i < 4; ++i) { pk[i] = f2bf(lo[i]); pk[4 + i] = f2bf(hi[i]); }
        }
        *(u16x8*)(ws16 + XB_OFF + e) = pk;
    }
    if (tid < NN * 11) {                       // adj: 11 8-elem chunks per row
        const int n = tid / 11;
        const int j = (tid - n * 11) * 8;
        u16x8 pk;
        #pragma unroll
        for (int m = 0; m < 8; ++m) {
            const int jj = j + m;
            pk[m] = (jj < 81) ? f2bf(adj[n * 81 + jj]) : (unsigned short)0;
        }
        *(u16x8*)(ws16 + ADJ_OFF + n * 88 + j) = pk;
    }
    if (tid < WST_ELE) {   // Wst[mch][o][kk] = conv_w[o][t*64 + c*32 + kk], mch=c*9+t
        const int kk = tid & 31, o = (tid >> 5) & 63, mch = tid >> 11;
        const int c = mch / 9, t = mch - 9 * c;
        ws16[WST_OFF + tid] = f2bf(conv_w[o * KC + t * 64 + c * 32 + kk]);
    }
    if (tid < WST2_ELE) {  // Wst2[c2][o][kk] = mlp_w[o][c2*32 + kk]
        const int kk = tid & 31, o = (tid >> 5) & 63, c2 = tid >> 11;
        ws16[WST2_OFF + tid] = f2bf(mlp_w[o * 64 + c2 * 32 + kk]);
    }
}

// ---------------------------------------------------------------------------
// Main fused kernel. GUARANTEED batch->XCD pinning: each block reads its real
// XCD (HW_REG_XCC_ID) and claims a chunk of that XCD's batch via per-XCD
// atomic counters. Pigeonhole: grid = 8*313 = sum of capacities, the first
// 313 increments of any counter are all successful claims, so the 8-attempt
// loop always finds a slot and every (batch,chunk) is claimed exactly once —
// correctness independent of the HW dispatch->XCD mapping.
// 1 wave = 16 rows; block = 4 waves.
// ---------------------------------------------------------------------------
__global__ void __launch_bounds__(256, 4) paiconv_main(
        const int*   __restrict__ nidx,     // [ROWS][9]
        const float* __restrict__ conv_b,   // [64]
        const float* __restrict__ mlp_b,    // [64]
        const unsigned short* __restrict__ ws16,
        int*         __restrict__ ctrs,     // [8] claim counters (in ws)
        float* __restrict__ out) {          // [ROWS][64]
    __shared__ float sm[4][16][68];
    __shared__ int s_claim;

    const int tx   = threadIdx.x;
    const int lane = tx & 63;
    const int l15  = lane & 15;
    const int q    = lane >> 4;
    const int wave = tx >> 6;

    // ---- claim a (batch, chunk) slot on this block's actual XCD ----
    if (tx == 0) {
        const int xcd = __builtin_amdgcn_s_getreg((31 << 11) | 20) & 7;  // HW_REG_XCC_ID
        int slot = 0;
        #pragma unroll 1
        for (int a = 0; a < 8; ++a) {
            const int xb = (xcd + a) & 7;
            const int c = atomicAdd(&ctrs[xb], 1);
            if (c < CHUNKS) { slot = xb * 512 + c; break; }
        }
        s_claim = slot;
    }
    __syncthreads();
    const int batch = s_claim >> 9;
    const int chunk = s_claim & 511;

    const int n0 = chunk * 64 + wave * 16;     // within-batch base row of wave
    if (n0 >= NN) return;                      // tail (chunk 312, waves 2,3)
    const int rowbase = batch * NN + n0;
    const int myrow   = rowbase + l15;
    const int myn     = n0 + l15;

    const unsigned short* Wst  = ws16 + WST_OFF;
    const unsigned short* Wst2 = ws16 + WST2_OFF;
    const unsigned short* Adj  = ws16 + ADJ_OFF;
    const unsigned short* XB   = ws16 + XB_OFF;
    const unsigned short* XBb  = XB + (size_t)batch * NN * 64;   // batch slice

    // ---- neighbor element-offsets within batch slice (rows pre-zeroed: no mask) ----
    int voff[KK];
    #pragma unroll
    for (int k = 0; k < KK; ++k) {
        const int idx = __builtin_nontemporal_load(nidx + myrow * KK + k);
        voff[k] = idx * 64 + q * 8;
    }

    // ---- adj row (81 bf16 padded 88) -> 44 dwords in regs (streaming: nt) ----
    unsigned adjw[44];
    {
        const u32x4* ap = (const u32x4*)(Adj + (size_t)myn * 88);
        #pragma unroll
        for (int u = 0; u < 11; ++u) {
            u32x4 w = __builtin_nontemporal_load(ap + u);
            adjw[4 * u + 0] = w.x; adjw[4 * u + 1] = w.y;
            adjw[4 * u + 2] = w.z; adjw[4 * u + 3] = w.w;
        }
    }

    f32x4 acc[4];    // conv accumulators (o-tiles of 16)
    f32x4 acc2[4];   // residual accumulators
    #pragma unroll
    for (int ot = 0; ot < 4; ++ot) { acc[ot] = (f32x4)0.0f; acc2[ot] = (f32x4)0.0f; }

    // ---- 2 f-halves (c) x 9 neighbor slots (t), MFMA K-chunk = 32 ----
    #pragma unroll 1
    for (int c = 0; c < 2; ++c) {
        float v[KK][8];
        #pragma unroll
        for (int k = 0; k < KK; ++k) {
            u16x8 pv = *(const u16x8*)(XBb + voff[k] + c * 32);   // L2-hit gather
            u32x4 pw = __builtin_bit_cast(u32x4, pv);
            v[k][0] = bflo2f(pw.x); v[k][1] = bfhi2f(pw.x);
            v[k][2] = bflo2f(pw.y); v[k][3] = bfhi2f(pw.y);
            v[k][4] = bflo2f(pw.z); v[k][5] = bfhi2f(pw.z);
            v[k][6] = bflo2f(pw.w); v[k][7] = bfhi2f(pw.w);
        }
        #pragma unroll
        for (int t = 0; t < KK; ++t) {
            float m[8] = {0.f,0.f,0.f,0.f,0.f,0.f,0.f,0.f};
            #pragma unroll
            for (int k = 0; k < KK; ++k) {
                const int j = k * 9 + t;                     // compile-time
                unsigned w = adjw[j >> 1];
                float a = (j & 1) ? bfhi2f(w) : bflo2f(w);
                #pragma unroll
                for (int i = 0; i < 8; ++i) m[i] = __builtin_fmaf(a, v[k][i], m[i]);
            }
            u16x8 pk;
            #pragma unroll
            for (int i = 0; i < 8; ++i) pk[i] = f2bf(elu_f(m[i]));
            bf16x8 afrag = __builtin_bit_cast(bf16x8, pk);
            const int mch = c * 9 + t;
            #pragma unroll
            for (int ot = 0; ot < 4; ++ot) {
                const u16x8* wp = (const u16x8*)(Wst + mch * 2048 + (ot * 16 + l15) * 32 + q * 8);
                bf16x8 bfrag = __builtin_bit_cast(bf16x8, *wp);
                acc[ot] = __builtin_amdgcn_mfma_f32_16x16x32_bf16(afrag, bfrag, acc[ot], 0, 0, 0);
            }
        }
    }

    // ---- residual GEMM: xb(row pre-masked) @ mlp_w^T, A-frag direct from XB ----
    #pragma unroll
    for (int c2 = 0; c2 < 2; ++c2) {
        bf16x8 a2 = *(const bf16x8*)(XB + (size_t)myrow * 64 + c2 * 32 + q * 8);
        #pragma unroll
        for (int ot = 0; ot < 4; ++ot) {
            const u16x8* wp = (const u16x8*)(Wst2 + c2 * 2048 + (ot * 16 + l15) * 32 + q * 8);
            bf16x8 b2 = __builtin_bit_cast(bf16x8, *wp);
            acc2[ot] = __builtin_amdgcn_mfma_f32_16x16x32_bf16(a2, b2, acc2[ot], 0, 0, 0);
        }
    }

    // ---- epilogue: elu(conv+cb)*mask + res + mb -> LDS transpose -> 1KB stores ----
    #pragma unroll
    for (int ot = 0; ot < 4; ++ot) {
        const int o = ot * 16 + l15;
        const float cb = conv_b[o];
        const float mb = mlp_b[o];
        #pragma unroll
        for (int i = 0; i < 4; ++i) {
            const int rr = 4 * q + i;                    // C/D: row = 4*(lane>>4)+reg
            float f = elu_f(acc[ot][i] + cb);
            if (n0 + rr == NN - 1) f = 0.0f;             // output mask
            f += acc2[ot][i] + mb;
            sm[wave][rr][o] = f;
        }
    }
    // wave-local LDS readback (no barrier needed), fully-contiguous 1KB stores
    #pragma unroll
    for (int p = 0; p < 4; ++p) {
        const int r = p * 4 + q;
        f32x4 vv = *(const f32x4*)&sm[wave][r][l15 * 4];
        __builtin_nontemporal_store(vv, (f32x4*)(out + (size_t)(rowbase + r) * 64 + l15 * 4));
    }
}

extern "C" void kernel_launch(void* const* d_in, const int* in_sizes, int n_in,
                              void* d_out, int out_size, void* d_ws, size_t ws_size,
                              hipStream_t stream) {
    const float* x      = (const float*)d_in[0];
    const int*   nidx   = (const int*)  d_in[1];
    const float* adj    = (const float*)d_in[2];
    const float* conv_w = (const float*)d_in[3];
    const float* conv_b = (const float*)d_in[4];
    const float* mlp_w  = (const float*)d_in[5];
    const float* mlp_b  = (const float*)d_in[6];
    unsigned short* ws16 = (unsigned short*)d_ws;
    int* ctrs = (int*)(ws16 + CTR_OFF);
    float* out = (float*)d_out;

    const int prep_blocks = (XB_ELE / 8) / 256;           // 5000
    paiconv_prep<<<prep_blocks, 256, 0, stream>>>(x, adj, conv_w, mlp_w, ws16);

    const int main_blocks = 8 * CHUNKS;                   // 2504, one claim each
    paiconv_main<<<main_blocks, 256, 0, stream>>>(nidx, conv_b, mlp_b, ws16, ctrs, out);
}

// Round 12
// 320.144 us; speedup vs baseline: 1.6562x; 1.6562x over previous
//
#include <hip/hip_runtime.h>

// ---- problem constants ----
#define BB 8
#define NN 20000
#define KK 9
#define KC 576                 // KK*64
#define ROWS (BB*NN)           // 160000
#define CHUNKS 313             // ceil(NN/64)

// ---- workspace layout (ushort elements) ----
#define WST_ELE   36864                 // conv_w chunks [18][64][32]
#define WST2_ELE  4096                  // mlp_w chunks  [2][64][32]
#define ADJ_ELE   (NN*88)               // adj rows padded 81->88 bf16
#define XB_ELE    (ROWS*64)             // x in bf16, row NN-1 per batch zeroed
#define WST_OFF   0
#define WST2_OFF  36864
#define ADJ_OFF   40960                 // byte 81,920 (16B aligned)
#define XB_OFF    (ADJ_OFF + ADJ_ELE)   // elem 1,800,960
#define CTR_OFF   (XB_OFF + XB_ELE)     // elem 12,040,960 -> byte 24,081,920 (64B aligned)
// total ws use: ~24.1 MB + 64 B

typedef __bf16 bf16x8 __attribute__((ext_vector_type(8)));
typedef float  f32x4  __attribute__((ext_vector_type(4)));
typedef unsigned short u16x8 __attribute__((ext_vector_type(8)));
typedef unsigned u32x4 __attribute__((ext_vector_type(4)));

__device__ __forceinline__ unsigned short f2bf(float f) {
    unsigned u = __builtin_bit_cast(unsigned, f);
    u += 0x7FFFu + ((u >> 16) & 1u);          // RNE
    return (unsigned short)(u >> 16);
}
__device__ __forceinline__ float bfhi2f(unsigned w) { return __builtin_bit_cast(float, w & 0xFFFF0000u); }
__device__ __forceinline__ float bflo2f(unsigned w) { return __builtin_bit_cast(float, w << 16); }
__device__ __forceinline__ float elu_f(float v) { return v > 0.0f ? v : (__expf(v) - 1.0f); }

// ---------------------------------------------------------------------------
// Prep: x -> bf16 (row NN-1 per batch zeroed), adj -> bf16 padded rows,
// conv_w / mlp_w -> MFMA chunk order, zero the 8 XCD claim counters.
// ---------------------------------------------------------------------------
__global__ void __launch_bounds__(256) paiconv_prep(
        const float* __restrict__ x,       // [ROWS][64]
        const float* __restrict__ adj,     // [NN][81]
        const float* __restrict__ conv_w,  // [64][576]
        const float* __restrict__ mlp_w,   // [64][64]
        unsigned short* __restrict__ ws16) {
    const int tid = blockIdx.x * 256 + threadIdx.x;

    if (tid < 16) {                            // claim counters (re-zeroed every launch)
        ((int*)(ws16 + CTR_OFF))[tid] = 0;
    }
    if (tid < XB_ELE / 8) {                    // 1,280,000 threads: 8 elems each
        const int e = tid * 8;
        const int r = e >> 6;                  // global row
        const int n = r % NN;                  // within-batch row
        u16x8 pk;
        if (n == NN - 1) {
            #pragma unroll
            for (int i = 0; i < 8; ++i) pk[i] = 0;   // pre-masked row
        } else {
            f32x4 lo = *(const f32x4*)(x + e);
            f32x4 hi = *(const f32x4*)(x + e + 4);
            #pragma unroll
            for (int i = 0; i < 4; ++i) { pk[i] = f2bf(lo[i]); pk[4 + i] = f2bf(hi[i]); }
        }
        *(u16x8*)(ws16 + XB_OFF + e) = pk;
    }
    if (tid < NN * 11) {                       // adj: 11 8-elem chunks per row
        const int n = tid / 11;
        const int j = (tid - n * 11) * 8;
        u16x8 pk;
        #pragma unroll
        for (int m = 0; m < 8; ++m) {
            const int jj = j + m;
            pk[m] = (jj < 81) ? f2bf(adj[n * 81 + jj]) : (unsigned short)0;
        }
        *(u16x8*)(ws16 + ADJ_OFF + n * 88 + j) = pk;
    }
    if (tid < WST_ELE) {   // Wst[mch][o][kk] = conv_w[o][t*64 + c*32 + kk], mch=c*9+t
        const int kk = tid & 31, o = (tid >> 5) & 63, mch = tid >> 11;
        const int c = mch / 9, t = mch - 9 * c;
        ws16[WST_OFF + tid] = f2bf(conv_w[o * KC + t * 64 + c * 32 + kk]);
    }
    if (tid < WST2_ELE) {  // Wst2[c2][o][kk] = mlp_w[o][c2*32 + kk]
        const int kk = tid & 31, o = (tid >> 5) & 63, c2 = tid >> 11;
        ws16[WST2_OFF + tid] = f2bf(mlp_w[o * 64 + c2 * 32 + kk]);
    }
}

// ---------------------------------------------------------------------------
// Main fused kernel. GUARANTEED batch->XCD pinning: each block reads its real
// XCD (HW_REG_XCC_ID) and claims a chunk of that XCD's batch via per-XCD
// atomic counters. Pigeonhole: every c<CHUNKS returned by a counter is used
// exactly once, and no block can fail all 8 attempts, so all (batch,chunk)
// slots are covered regardless of the HW dispatch->XCD mapping.
// 1 wave = 16 rows; block = 4 waves. (256,2): VGPR 128, no spill (R11 lesson).
// ---------------------------------------------------------------------------
__global__ void __launch_bounds__(256, 2) paiconv_main(
        const int*   __restrict__ nidx,     // [ROWS][9]
        const float* __restrict__ conv_b,   // [64]
        const float* __restrict__ mlp_b,    // [64]
        const unsigned short* __restrict__ ws16,
        int*         __restrict__ ctrs,     // [8] claim counters (in ws)
        float* __restrict__ out) {          // [ROWS][64]
    __shared__ float sm[4][16][68];
    __shared__ int s_claim;

    const int tx   = threadIdx.x;
    const int lane = tx & 63;
    const int l15  = lane & 15;
    const int q    = lane >> 4;
    const int wave = tx >> 6;

    // ---- claim a (batch, chunk) slot on this block's actual XCD ----
    if (tx == 0) {
        const int xcd = __builtin_amdgcn_s_getreg((31 << 11) | 20) & 7;  // HW_REG_XCC_ID
        int slot = 0;
        #pragma unroll 1
        for (int a = 0; a < 8; ++a) {
            const int xb = (xcd + a) & 7;
            const int c = atomicAdd(&ctrs[xb], 1);
            if (c < CHUNKS) { slot = xb * 512 + c; break; }
        }
        s_claim = slot;
    }
    __syncthreads();
    const int batch = s_claim >> 9;
    const int chunk = s_claim & 511;

    const int n0 = chunk * 64 + wave * 16;     // within-batch base row of wave
    if (n0 >= NN) return;                      // tail (chunk 312, waves 2,3)
    const int rowbase = batch * NN + n0;
    const int myrow   = rowbase + l15;
    const int myn     = n0 + l15;

    const unsigned short* Wst  = ws16 + WST_OFF;
    const unsigned short* Wst2 = ws16 + WST2_OFF;
    const unsigned short* Adj  = ws16 + ADJ_OFF;
    const unsigned short* XB   = ws16 + XB_OFF;
    const unsigned short* XBb  = XB + (size_t)batch * NN * 64;   // batch slice

    // ---- neighbor element-offsets within batch slice (rows pre-zeroed: no mask) ----
    int voff[KK];
    #pragma unroll
    for (int k = 0; k < KK; ++k) {
        const int idx = __builtin_nontemporal_load(nidx + myrow * KK + k);
        voff[k] = idx * 64 + q * 8;
    }

    // ---- adj row (81 bf16 padded 88) -> 44 dwords in regs (streaming: nt) ----
    unsigned adjw[44];
    {
        const u32x4* ap = (const u32x4*)(Adj + (size_t)myn * 88);
        #pragma unroll
        for (int u = 0; u < 11; ++u) {
            u32x4 w = __builtin_nontemporal_load(ap + u);
            adjw[4 * u + 0] = w.x; adjw[4 * u + 1] = w.y;
            adjw[4 * u + 2] = w.z; adjw[4 * u + 3] = w.w;
        }
    }

    f32x4 acc[4];    // conv accumulators (o-tiles of 16)
    f32x4 acc2[4];   // residual accumulators
    #pragma unroll
    for (int ot = 0; ot < 4; ++ot) { acc[ot] = (f32x4)0.0f; acc2[ot] = (f32x4)0.0f; }

    // ---- 2 f-halves (c) x 9 neighbor slots (t), MFMA K-chunk = 32 ----
    #pragma unroll 1
    for (int c = 0; c < 2; ++c) {
        float v[KK][8];
        #pragma unroll
        for (int k = 0; k < KK; ++k) {
            u16x8 pv = *(const u16x8*)(XBb + voff[k] + c * 32);   // L2-hit gather
            u32x4 pw = __builtin_bit_cast(u32x4, pv);
            v[k][0] = bflo2f(pw.x); v[k][1] = bfhi2f(pw.x);
            v[k][2] = bflo2f(pw.y); v[k][3] = bfhi2f(pw.y);
            v[k][4] = bflo2f(pw.z); v[k][5] = bfhi2f(pw.z);
            v[k][6] = bflo2f(pw.w); v[k][7] = bfhi2f(pw.w);
        }
        #pragma unroll
        for (int t = 0; t < KK; ++t) {
            float m[8] = {0.f,0.f,0.f,0.f,0.f,0.f,0.f,0.f};
            #pragma unroll
            for (int k = 0; k < KK; ++k) {
                const int j = k * 9 + t;                     // compile-time
                unsigned w = adjw[j >> 1];
                float a = (j & 1) ? bfhi2f(w) : bflo2f(w);
                #pragma unroll
                for (int i = 0; i < 8; ++i) m[i] = __builtin_fmaf(a, v[k][i], m[i]);
            }
            u16x8 pk;
            #pragma unroll
            for (int i = 0; i < 8; ++i) pk[i] = f2bf(elu_f(m[i]));
            bf16x8 afrag = __builtin_bit_cast(bf16x8, pk);
            const int mch = c * 9 + t;
            #pragma unroll
            for (int ot = 0; ot < 4; ++ot) {
                const u16x8* wp = (const u16x8*)(Wst + mch * 2048 + (ot * 16 + l15) * 32 + q * 8);
                bf16x8 bfrag = __builtin_bit_cast(bf16x8, *wp);
                acc[ot] = __builtin_amdgcn_mfma_f32_16x16x32_bf16(afrag, bfrag, acc[ot], 0, 0, 0);
            }
        }
    }

    // ---- residual GEMM: xb(row pre-masked) @ mlp_w^T, A-frag direct from XB ----
    #pragma unroll
    for (int c2 = 0; c2 < 2; ++c2) {
        bf16x8 a2 = *(const bf16x8*)(XB + (size_t)myrow * 64 + c2 * 32 + q * 8);
        #pragma unroll
        for (int ot = 0; ot < 4; ++ot) {
            const u16x8* wp = (const u16x8*)(Wst2 + c2 * 2048 + (ot * 16 + l15) * 32 + q * 8);
            bf16x8 b2 = __builtin_bit_cast(bf16x8, *wp);
            acc2[ot] = __builtin_amdgcn_mfma_f32_16x16x32_bf16(a2, b2, acc2[ot], 0, 0, 0);
        }
    }

    // ---- epilogue: elu(conv+cb)*mask + res + mb -> LDS transpose ----
    #pragma unroll
    for (int ot = 0; ot < 4; ++ot) {
        const int o = ot * 16 + l15;
        const float cb = conv_b[o];
        const float mb = mlp_b[o];
        #pragma unroll
        for (int i = 0; i < 4; ++i) {
            const int rr = 4 * q + i;                    // C/D: row = 4*(lane>>4)+reg
            float f = elu_f(acc[ot][i] + cb);
            if (n0 + rr == NN - 1) f = 0.0f;             // output mask
            f += acc2[ot][i] + mb;
            sm[wave][rr][o] = f;
        }
    }
    // wave-local LDS readback; PLAIN stores (write-back L2 combines full lines;
    // NT stores fragmented to 64B partials = 4x WRITE amplification, R10 lesson)
    #pragma unroll
    for (int p = 0; p < 4; ++p) {
        const int r = p * 4 + q;
        f32x4 vv = *(const f32x4*)&sm[wave][r][l15 * 4];
        *(f32x4*)(out + (size_t)(rowbase + r) * 64 + l15 * 4) = vv;
    }
}

extern "C" void kernel_launch(void* const* d_in, const int* in_sizes, int n_in,
                              void* d_out, int out_size, void* d_ws, size_t ws_size,
                              hipStream_t stream) {
    const float* x      = (const float*)d_in[0];
    const int*   nidx   = (const int*)  d_in[1];
    const float* adj    = (const float*)d_in[2];
    const float* conv_w = (const float*)d_in[3];
    const float* conv_b = (const float*)d_in[4];
    const float* mlp_w  = (const float*)d_in[5];
    const float* mlp_b  = (const float*)d_in[6];
    unsigned short* ws16 = (unsigned short*)d_ws;
    int* ctrs = (int*)(ws16 + CTR_OFF);
    float* out = (float*)d_out;

    const int prep_blocks = (XB_ELE / 8) / 256;           // 5000
    paiconv_prep<<<prep_blocks, 256, 0, stream>>>(x, adj, conv_w, mlp_w, ws16);

    const int main_blocks = 8 * CHUNKS;                   // 2504, one claim each
    paiconv_main<<<main_blocks, 256, 0, stream>>>(nidx, conv_b, mlp_b, ws16, ctrs, out);
}

// Round 13
// 252.710 us; speedup vs baseline: 2.0981x; 1.2668x over previous
//
#include <hip/hip_runtime.h>

// ---- problem constants ----
#define BB 8
#define NN 20000
#define KK 9
#define KC 576                 // KK*64
#define ROWS (BB*NN)           // 160000

// ---- workspace layout (ushort elements) ----
#define WST_ELE   36864                 // conv_w chunks [18][64][32]
#define WST2_ELE  4096                  // mlp_w chunks  [2][64][32]
#define XB_ELE    (ROWS*64)             // x in bf16, row NN-1 per batch zeroed
#define WST_OFF   0
#define WST2_OFF  36864
#define XB_OFF    40960                 // byte 81,920 (16B aligned)
// total ws use: 20,520,960 ushort = 20.5 MB

#define PSTRIDE 584                     // P row stride in ushort (576 + 8 pad)

typedef __bf16 bf16x8 __attribute__((ext_vector_type(8)));
typedef float  f32x4  __attribute__((ext_vector_type(4)));
typedef unsigned short u16x8 __attribute__((ext_vector_type(8)));

__device__ __forceinline__ unsigned short f2bf(float f) {
    unsigned u = __builtin_bit_cast(unsigned, f);
    u += 0x7FFFu + ((u >> 16) & 1u);          // RNE
    return (unsigned short)(u >> 16);
}
__device__ __forceinline__ float bf2f(unsigned short h) {
    return __builtin_bit_cast(float, ((unsigned)h) << 16);
}
__device__ __forceinline__ float elu_f(float v) { return v > 0.0f ? v : (__expf(v) - 1.0f); }

// ---------------------------------------------------------------------------
// Prep: x -> bf16 (row NN-1 per batch zeroed), conv_w / mlp_w -> chunk order.
// ---------------------------------------------------------------------------
__global__ void __launch_bounds__(256) paiconv_prep(
        const float* __restrict__ x,       // [ROWS][64]
        const float* __restrict__ conv_w,  // [64][576]
        const float* __restrict__ mlp_w,   // [64][64]
        unsigned short* __restrict__ ws16) {
    const int tid = blockIdx.x * 256 + threadIdx.x;

    if (tid < XB_ELE / 8) {                    // 1,280,000 threads: 8 elems each
        const int e = tid * 8;
        const int r = e >> 6;                  // global row
        const int n = r % NN;                  // within-batch row
        u16x8 pk;
        if (n == NN - 1) {
            #pragma unroll
            for (int i = 0; i < 8; ++i) pk[i] = 0;   // pre-masked row
        } else {
            f32x4 lo = *(const f32x4*)(x + e);
            f32x4 hi = *(const f32x4*)(x + e + 4);
            #pragma unroll
            for (int i = 0; i < 4; ++i) { pk[i] = f2bf(lo[i]); pk[4 + i] = f2bf(hi[i]); }
        }
        *(u16x8*)(ws16 + XB_OFF + e) = pk;
    }
    if (tid < WST_ELE) {   // Wst[mch][o][kk] = conv_w[o][t*64 + c*32 + kk], mch=c*9+t
        const int kk = tid & 31, o = (tid >> 5) & 63, mch = tid >> 11;
        const int c = mch / 9, t = mch - 9 * c;
        ws16[WST_OFF + tid] = f2bf(conv_w[o * KC + t * 64 + c * 32 + kk]);
    }
    if (tid < WST2_ELE) {  // Wst2[c2][o][kk] = mlp_w[o][c2*32 + kk]
        const int kk = tid & 31, o = (tid >> 5) & 63, c2 = tid >> 11;
        ws16[WST2_OFF + tid] = f2bf(mlp_w[o * 64 + c2 * 32 + kk]);
    }
}

// ---------------------------------------------------------------------------
// Main. One wave = 16 rows. Phase 1 (per row, lane=feature): 9 single-line
// coalesced bf16-row gathers (scalar base), 9x9 mix with wave-uniform adj
// scalars, ELU, write P-row to LDS. Phase 2: MFMA conv GEMM from LDS A-frags
// + residual GEMM + fused epilogue. 2 waves/block, no barriers.
// ---------------------------------------------------------------------------
__global__ void __launch_bounds__(128, 2) paiconv_main(
        const int*   __restrict__ nidx,     // [ROWS][9] (int32 on device)
        const float* __restrict__ adj,      // [NN][81] fp32
        const float* __restrict__ conv_b,   // [64]
        const float* __restrict__ mlp_b,    // [64]
        const unsigned short* __restrict__ ws16,
        float* __restrict__ out) {          // [ROWS][64]
    __shared__ unsigned short P[2][16 * PSTRIDE];   // 37,376 B

    const int tx   = threadIdx.x;
    const int lane = tx & 63;
    const int l15  = lane & 15;
    const int q    = lane >> 4;
    const int wave = __builtin_amdgcn_readfirstlane(tx >> 6);
    const int batch = blockIdx.x & 7;
    const int chunk = blockIdx.x >> 3;          // 0..624
    const int n0    = chunk * 32 + wave * 16;   // within-batch base row (20000 = 625*32)
    const int rowbase = batch * NN + n0;

    const unsigned short* Wst  = ws16 + WST_OFF;
    const unsigned short* Wst2 = ws16 + WST2_OFF;
    const unsigned short* XB   = ws16 + XB_OFF;
    const unsigned short* XBb  = XB + (size_t)batch * NN * 64;   // batch slice
    unsigned short* Pw = &P[wave][0];

    // ---- phase 1: per-row gather + mix + ELU -> LDS ----
    #pragma unroll 2
    for (int r = 0; r < 16; ++r) {
        const int n    = n0 + r;                 // uniform
        const int grow = rowbase + r;            // uniform
        const float* adjrow = adj + (size_t)n * 81;

        float vf[KK];
        #pragma unroll
        for (int k = 0; k < KK; ++k) {
            const int idx = __builtin_amdgcn_readfirstlane(nidx[grow * KK + k]);
            const unsigned short* rp = XBb + idx * 64;   // uniform base
            vf[k] = bf2f(rp[lane]);                      // 1 line / instruction
        }
        float m[KK] = {0.f,0.f,0.f,0.f,0.f,0.f,0.f,0.f,0.f};
        #pragma unroll
        for (int k = 0; k < KK; ++k) {
            #pragma unroll
            for (int t = 0; t < KK; ++t)
                m[t] = __builtin_fmaf(adjrow[k * 9 + t], vf[k], m[t]);  // SGPR * VGPR
        }
        #pragma unroll
        for (int t = 0; t < KK; ++t)
            Pw[r * PSTRIDE + t * 64 + lane] = f2bf(elu_f(m[t]));
    }

    // ---- phase 2: conv GEMM from LDS A-frags ----
    f32x4 acc[4];    // conv accumulators (o-tiles of 16)
    f32x4 acc2[4];   // residual accumulators
    #pragma unroll
    for (int ot = 0; ot < 4; ++ot) { acc[ot] = (f32x4)0.0f; acc2[ot] = (f32x4)0.0f; }

    #pragma unroll
    for (int c = 0; c < 2; ++c) {
        #pragma unroll
        for (int t = 0; t < KK; ++t) {
            const u16x8* ap = (const u16x8*)(Pw + l15 * PSTRIDE + t * 64 + c * 32 + q * 8);
            bf16x8 afrag = __builtin_bit_cast(bf16x8, *ap);
            const int mch = c * 9 + t;
            #pragma unroll
            for (int ot = 0; ot < 4; ++ot) {
                const u16x8* wp = (const u16x8*)(Wst + mch * 2048 + (ot * 16 + l15) * 32 + q * 8);
                bf16x8 bfrag = __builtin_bit_cast(bf16x8, *wp);
                acc[ot] = __builtin_amdgcn_mfma_f32_16x16x32_bf16(afrag, bfrag, acc[ot], 0, 0, 0);
            }
        }
    }

    // ---- residual GEMM: xb(row pre-masked) @ mlp_w^T ----
    #pragma unroll
    for (int c2 = 0; c2 < 2; ++c2) {
        bf16x8 a2 = *(const bf16x8*)(XB + (size_t)(rowbase + l15) * 64 + c2 * 32 + q * 8);
        #pragma unroll
        for (int ot = 0; ot < 4; ++ot) {
            const u16x8* wp = (const u16x8*)(Wst2 + c2 * 2048 + (ot * 16 + l15) * 32 + q * 8);
            bf16x8 b2 = __builtin_bit_cast(bf16x8, *wp);
            acc2[ot] = __builtin_amdgcn_mfma_f32_16x16x32_bf16(a2, b2, acc2[ot], 0, 0, 0);
        }
    }

    // ---- epilogue: elu(conv+cb)*mask + res + mb -> LDS transpose (reuse P) ----
    float* smf = (float*)Pw;                     // 16 x 68 f32 fits in P region
    #pragma unroll
    for (int ot = 0; ot < 4; ++ot) {
        const int o = ot * 16 + l15;
        const float cb = conv_b[o];
        const float mb = mlp_b[o];
        #pragma unroll
        for (int i = 0; i < 4; ++i) {
            const int rr = 4 * q + i;                    // C/D: row = 4*(lane>>4)+reg
            float f = elu_f(acc[ot][i] + cb);
            if (n0 + rr == NN - 1) f = 0.0f;             // output mask
            f += acc2[ot][i] + mb;
            smf[rr * 68 + o] = f;
        }
    }
    #pragma unroll
    for (int p = 0; p < 4; ++p) {
        const int r = p * 4 + q;
        f32x4 vv = *(const f32x4*)&smf[r * 68 + l15 * 4];
        *(f32x4*)(out + (size_t)(rowbase + r) * 64 + l15 * 4) = vv;
    }
}

extern "C" void kernel_launch(void* const* d_in, const int* in_sizes, int n_in,
                              void* d_out, int out_size, void* d_ws, size_t ws_size,
                              hipStream_t stream) {
    const float* x      = (const float*)d_in[0];
    const int*   nidx   = (const int*)  d_in[1];
    const float* adj    = (const float*)d_in[2];
    const float* conv_w = (const float*)d_in[3];
    const float* conv_b = (const float*)d_in[4];
    const float* mlp_w  = (const float*)d_in[5];
    const float* mlp_b  = (const float*)d_in[6];
    unsigned short* ws16 = (unsigned short*)d_ws;
    float* out = (float*)d_out;

    const int prep_blocks = (XB_ELE / 8) / 256;           // 5000
    paiconv_prep<<<prep_blocks, 256, 0, stream>>>(x, conv_w, mlp_w, ws16);

    const int main_blocks = 8 * 625;                      // batch = bid&7, chunk = bid>>3
    paiconv_main<<<main_blocks, 128, 0, stream>>>(nidx, adj, conv_b, mlp_b, ws16, out);
}